// Round 15
// baseline (101.196 us; speedup 1.0000x reference)
//
#include <hip/hip_runtime.h>
#include <math.h>
#include <limits.h>

namespace {
constexpr int BB   = 4;
constexpr int NCH  = 6;
constexpr int HH   = 512;
constexpr int WW   = 512;
constexpr int NCEN = 64;
constexpr int KSZ  = 21;
constexpr int PADR = 10;
constexpr int HW   = HH * WW;
constexpr int BOXSTRIDE = 640;       // per-(b,ci) blurbox slot (25*25 rounded up)

__device__ __forceinline__ int refl(int q, int n) {
    q = (q < 0) ? -q : q;
    q = (q >= n) ? (2 * n - 2 - q) : q;
    return q;
}

// ---------------------------------------------------------------------------
// Fused kernel: per-tile geometry (all 256 x-blocks) + sparse blur (x-blocks
// 0..63 additionally blur center ci=tIdx; mask recomputed inline from centers
// -> no dense mask buffer, no k_geom->blur dependency, blur hides under the
// other blocks' geometry). Per-center max goes to maxslot[b][ci] via plain
// store (no atomics, no zero-init ordering). R13 lesson: never serialize the
// normalize on one block; R7/R8 lesson: atan2f stays (poly absmax 1.6e-2).
// Argmin key 64*d2+i, exact ints, strict-min == jnp.argmin tie-break; tile /
// patch pruning conservative (pruned j: d2_j > ub >= d2_win strictly).
// ---------------------------------------------------------------------------
__global__ __launch_bounds__(256) void k_geom_blur(
    const float* __restrict__ centers,   // [B][NCEN][2] (cy, cx)
    const float* __restrict__ gt,        // [B][6][H][W]
    const float* __restrict__ g2d,       // [21][21]
    float* __restrict__ out,             // [B][6][H][W]
    float* __restrict__ blurbox,         // [B][NCEN][BOXSTRIDE]
    float* __restrict__ maxslot)         // [B][NCEN]
{
    __shared__ float s_cxf[NCEN], s_cyf[NCEN];
    __shared__ int   s_kx[NCEN], s_ky8[NCEN], s_ki[NCEN];
    __shared__ int   s_cnt, s_hasv;

    const int b    = blockIdx.y;
    const int tid  = threadIdx.x;
    const int tIdx = blockIdx.x;          // 0..255
    const int r0   = (tIdx >> 4) * 32;    // tile row base (h)
    const int c0   = (tIdx & 15) * 32;    // tile col base (w)

    // ---- tile prune (wave 0) ----
    if (tid < NCEN) {
        float cy = centers[(b * NCEN + tid) * 2 + 0];
        float cx = centers[(b * NCEN + tid) * 2 + 1];
        bool valid = (cy > 0.0f) || (cx > 0.0f);
        s_cxf[tid] = cx;
        s_cyf[tid] = cy;
        float r0f = (float)r0, r1f = (float)(r0 + 31);
        float c0f = (float)c0, c1f = (float)(c0 + 31);
        float drm = fmaxf(fmaxf(r0f - cx, cx - r1f), 0.0f);
        float dcm = fmaxf(fmaxf(c0f - cy, cy - c1f), 0.0f);
        float drM = fmaxf(cx - r0f, r1f - cx);
        float dcM = fmaxf(cy - c0f, c1f - cy);
        float mind2 = drm * drm + dcm * dcm;   // exact ints in f32
        float maxd2 = drM * drM + dcM * dcM;
        if (!valid) { mind2 = __int_as_float(0x7f800000); maxd2 = mind2; }
        float ub = maxd2;
#pragma unroll
        for (int off = 32; off > 0; off >>= 1)
            ub = fminf(ub, __shfl_xor(ub, off, 64));
        bool keep = valid && (mind2 <= ub);
        unsigned long long km = __ballot(keep);
        unsigned long long vm = __ballot(valid);
        if (keep) {
            int pos = __popcll(km & ((1ull << tid) - 1ull));
            s_kx[pos]  = (int)cx;
            s_ky8[pos] = ((int)cy) * 8;
            s_ki[pos]  = tid;
        }
        if (tid == 0) { s_cnt = (int)__popcll(km); s_hasv = (vm != 0ull) ? 1 : 0; }
    }
    __syncthreads();

    // ---- geometry: 32 rows x 8 threads/row, 4 px/thread ----
    {
        const int row = r0 + (tid >> 3);
        const int wb  = c0 + (tid & 7) * 4;
        const int w8  = wb * 8;
        const int cnt = s_cnt;
        const bool hv = (s_hasv != 0);

        int b0 = INT_MAX, b1 = INT_MAX, b2 = INT_MAX, b3 = INT_MAX;
        for (int k = 0; k < cnt; ++k) {
            int dr   = row - s_kx[k];
            int base = (__mul24(dr, dr) << 6) + s_ki[k];   // 64*dr^2 + i
            int icy8 = s_ky8[k];
            int d0 = w8      - icy8; b0 = min(b0, __mul24(d0, d0) + base);
            int d1 = w8 + 8  - icy8; b1 = min(b1, __mul24(d1, d1) + base);
            int d2 = w8 + 16 - icy8; b2 = min(b2, __mul24(d2, d2) + base);
            int d3 = w8 + 24 - icy8; b3 = min(b3, __mul24(d3, d3) + base);
        }
        int bi[4] = { b0 & 63, b1 & 63, b2 & 63, b3 & 63 };

        float aR[4], aT[4], aS[4], aC[4];
        const float fh = (float)row;
#pragma unroll
        for (int j = 0; j < 4; ++j) {
            float cxw = s_cxf[bi[j]];
            float cyw = s_cyf[bi[j]];
            float gX = cxw - fh;
            float gY = cyw - (float)(wb + j);
            float r2 = gX * gX + gY * gY;
            bool rpos = r2 > 0.0f;
            float R = rpos ? sqrtf(r2) : 0.0f;
            aR[j] = R;
            aT[j] = atan2f(gY, rpos ? gX : 1.0f);
            float invR = rpos ? (1.0f / R) : 0.0f;
            aS[j] = rpos ? gY * invR : 0.0f;   // sin(atan2) == gY/R
            aC[j] = rpos ? gX * invR : 1.0f;   // cos(atan2) == gX/R
        }

        const size_t base = (size_t)b * NCH * HW + (size_t)(row * WW + wb);
        if (hv) {
            *(float4*)&out[base + 0 * (size_t)HW] = make_float4(aR[0], aR[1], aR[2], aR[3]);
            *(float4*)&out[base + 1 * (size_t)HW] = make_float4(aT[0], aT[1], aT[2], aT[3]);
            *(float4*)&out[base + 2 * (size_t)HW] = make_float4(aS[0], aS[1], aS[2], aS[3]);
            *(float4*)&out[base + 3 * (size_t)HW] = make_float4(aC[0], aC[1], aC[2], aC[3]);
        } else {
            *(float4*)&out[base + 0 * (size_t)HW] = *(const float4*)&gt[base + 0 * (size_t)HW];
            *(float4*)&out[base + 1 * (size_t)HW] = *(const float4*)&gt[base + 1 * (size_t)HW];
            *(float4*)&out[base + 2 * (size_t)HW] = *(const float4*)&gt[base + 2 * (size_t)HW];
            *(float4*)&out[base + 3 * (size_t)HW] = *(const float4*)&gt[base + 3 * (size_t)HW];
        }
        *(float4*)&out[base + 4 * (size_t)HW] = *(const float4*)&gt[base + 4 * (size_t)HW];
        *(float4*)&out[base + 5 * (size_t)HW] = make_float4(0.f, 0.f, 0.f, 0.f);
    }

    // ---- blur phase: blocks 0..63 handle center ci = tIdx ----
    if (tIdx >= NCEN) return;             // block-uniform exit
    const int ci = tIdx;
    const float ccy = s_cyf[ci], ccx = s_cxf[ci];
    if (!((ccy > 0.0f) || (ccx > 0.0f))) {
        if (tid == 0) maxslot[b * NCEN + ci] = 0.0f;   // slot must be defined
        return;                            // block-uniform exit
    }
    const int icx = (int)ccx, icy = (int)ccy;
    const int rA = max(icx - 12, 0), rB = min(icx + 12, HH - 1);
    const int cA = max(icy - 12, 0), cB = min(icy + 12, WW - 1);
    const int pr0 = max(rA - PADR, 0), pr1 = min(rB + PADR, HH - 1);
    const int pc0 = max(cA - PADR, 0), pc1 = min(cB + PADR, WW - 1);
    const int nr = pr1 - pr0 + 1, nc = pc1 - pc0 + 1;   // <= 45
    const int nh = rB - rA + 1,  nw = cB - cA + 1;      // <= 25

    __shared__ float k1[KSZ];
    __shared__ float patch[45 * 48];
    __shared__ float tmp[25 * 46];
    __shared__ float swr[4];

    __syncthreads();                      // geometry done reading s_k*

    // re-prune for the patch box (wave 0) + 1D kernel row sums
    if (tid < NCEN) {
        float cy = s_cyf[tid], cx = s_cxf[tid];
        bool valid = (cy > 0.0f) || (cx > 0.0f);
        float r0f = (float)pr0, r1f = (float)pr1;
        float c0f = (float)pc0, c1f = (float)pc1;
        float drm = fmaxf(fmaxf(r0f - cx, cx - r1f), 0.0f);
        float dcm = fmaxf(fmaxf(c0f - cy, cy - c1f), 0.0f);
        float drM = fmaxf(cx - r0f, r1f - cx);
        float dcM = fmaxf(cy - c0f, c1f - cy);
        float mind2 = drm * drm + dcm * dcm;
        float maxd2 = drM * drM + dcM * dcM;
        if (!valid) { mind2 = __int_as_float(0x7f800000); maxd2 = mind2; }
        float ub = maxd2;
#pragma unroll
        for (int off = 32; off > 0; off >>= 1)
            ub = fminf(ub, __shfl_xor(ub, off, 64));
        bool keep = valid && (mind2 <= ub);
        unsigned long long km = __ballot(keep);
        if (keep) {
            int pos = __popcll(km & ((1ull << tid) - 1ull));
            s_kx[pos]  = (int)cx;
            s_ky8[pos] = ((int)cy) * 8;
            s_ki[pos]  = tid;
        }
        if (tid == 0) s_cnt = (int)__popcll(km);
    }
    if (tid < KSZ) {
        float s = 0.0f;
#pragma unroll
        for (int j = 0; j < KSZ; ++j) s += g2d[tid * KSZ + j];
        k1[tid] = s;                      // exact 1D factor: row sums of g2d
    }
    __syncthreads();

    // inline mask over the patch: argmin winner within 3px box -> 1.0
    const int cnt2 = s_cnt;
    for (int e = tid; e < nr * nc; e += 256) {
        int r = e / nc, c = e - r * nc;
        int h = pr0 + r, w8 = (pc0 + c) * 8;
        int best = INT_MAX;
        for (int k = 0; k < cnt2; ++k) {
            int dr = h - s_kx[k];
            int dc = w8 - s_ky8[k];
            best = min(best, (__mul24(dr, dr) << 6) + __mul24(dc, dc) + s_ki[k]);
        }
        int bi2 = best & 63;
        float gX = s_cxf[bi2] - (float)h;
        float gY = s_cyf[bi2] - (float)(pc0 + c);
        patch[r * 48 + c] =
            ((fabsf(gX) < 3.0f) && (fabsf(gY) < 3.0f)) ? 1.0f : 0.0f;
    }
    __syncthreads();

    for (int e = tid; e < nh * nc; e += 256) {
        int lr = e / nc, j = e - lr * nc;
        int r  = rA + lr;
        float acc = 0.0f;
#pragma unroll
        for (int dv = -PADR; dv <= PADR; ++dv) {
            int q = refl(r + dv, HH);
            acc = fmaf(k1[dv + PADR], patch[(q - pr0) * 48 + j], acc);
        }
        tmp[lr * 46 + j] = acc;
    }
    __syncthreads();

    float vmax = 0.0f;
    float* bx = blurbox + (size_t)(b * NCEN + ci) * BOXSTRIDE;
    for (int e = tid; e < nh * nw; e += 256) {
        int lr = e / nw, j = e - lr * nw;
        int w  = cA + j;
        float acc = 0.0f;
#pragma unroll
        for (int d = -PADR; d <= PADR; ++d) {
            int q = refl(w + d, WW);
            acc = fmaf(k1[d + PADR], tmp[lr * 46 + (q - pc0)], acc);
        }
        bx[lr * 25 + j] = acc;
        vmax = fmaxf(vmax, acc);
    }
#pragma unroll
    for (int off = 32; off > 0; off >>= 1)
        vmax = fmaxf(vmax, __shfl_down(vmax, off, 64));
    const int lane = tid & 63, wid = tid >> 6;
    if (lane == 0) swr[wid] = vmax;
    __syncthreads();
    if (tid == 0) {
        float m = fmaxf(fmaxf(swr[0], swr[1]), fmaxf(swr[2], swr[3]));
        maxslot[b * NCEN + ci] = m;        // plain store, no atomics
    }
}

// ---------------------------------------------------------------------------
// Normalize: per-center block reduces the 64 maxslot values in-wave (max is
// order-exact), scales its stored box, writes ch5. Overlapping boxes write
// bit-identical values.
// ---------------------------------------------------------------------------
__global__ __launch_bounds__(256) void k_norm_sparse(
    const float* __restrict__ centers,
    const float* __restrict__ blurbox,
    const float* __restrict__ maxslot,
    float* __restrict__ out)
{
    const int b   = blockIdx.y;
    const int ci  = blockIdx.x;
    const int tid = threadIdx.x;
    float cy = centers[(b * NCEN + ci) * 2 + 0];
    float cx = centers[(b * NCEN + ci) * 2 + 1];
    if (!((cy > 0.0f) || (cx > 0.0f))) return;
    const int icx = (int)cx, icy = (int)cy;
    const int rA = max(icx - 12, 0), rB = min(icx + 12, HH - 1);
    const int cA = max(icy - 12, 0), cB = min(icy + 12, WW - 1);
    const int nh = rB - rA + 1, nw = cB - cA + 1;

    __shared__ float s_inv;
    if (tid < NCEN) {                     // wave 0: reduce 64 slots
        float v = maxslot[b * NCEN + tid];
#pragma unroll
        for (int off = 32; off > 0; off >>= 1)
            v = fmaxf(v, __shfl_xor(v, off, 64));
        if (tid == 0) s_inv = 1.0f / fmaxf(v, 1e-12f);
    }
    __syncthreads();

    const float inv = s_inv;
    const float* bx = blurbox + (size_t)(b * NCEN + ci) * BOXSTRIDE;
    float* o5 = out + ((size_t)b * NCH + 5) * HW;
    for (int e = tid; e < nh * nw; e += 256) {
        int lr = e / nw, j = e - lr * nw;
        o5[(rA + lr) * WW + (cA + j)] = bx[lr * 25 + j] * inv;  // overwrites zeros
    }
}

} // namespace

extern "C" void kernel_launch(void* const* d_in, const int* in_sizes, int n_in,
                              void* d_out, int out_size, void* d_ws, size_t ws_size,
                              hipStream_t stream) {
    (void)in_sizes; (void)n_in; (void)out_size; (void)ws_size;
    const float* centers = (const float*)d_in[0];
    const float* gt      = (const float*)d_in[1];
    const float* g2d     = (const float*)d_in[2];
    float* out     = (float*)d_out;
    float* blurbox = (float*)d_ws;                               // BB*NCEN*640 floats
    float* maxslot = blurbox + (size_t)BB * NCEN * BOXSTRIDE;    // BB*NCEN floats

    dim3 gridG(256, BB);                  // 16x16 tiles; x<64 also blur center x
    k_geom_blur<<<gridG, 256, 0, stream>>>(centers, gt, g2d, out, blurbox, maxslot);
    dim3 gridS(NCEN, BB);
    k_norm_sparse<<<gridS, 256, 0, stream>>>(centers, blurbox, maxslot, out);
}